// Round 1
// baseline (918.395 us; speedup 1.0000x reference)
//
#include <hip/hip_runtime.h>
#include <hip/hip_bf16.h>
#include <cstdint>
#include <cstddef>

// Problem constants
#define K_DIM   4096          // INF
#define N_DIM   11008         // OUTF
#define M_DIM   4096          // 2*2048
#define GROUPS  32
#define QROWS   512           // INF*4/32

typedef __bf16 bf16x8 __attribute__((ext_vector_type(8)));
typedef float  f32x4  __attribute__((ext_vector_type(4)));

// ---------------------------------------------------------------------------
// async 16B global -> LDS (wave-uniform LDS base + lane*16 semantics)
// ---------------------------------------------------------------------------
__device__ __forceinline__ void async16(const void* g, void* lds) {
    __builtin_amdgcn_global_load_lds(
        (const __attribute__((address_space(1))) uint32_t*)g,
        (__attribute__((address_space(3))) uint32_t*)lds,
        16, 0, 0);
}

// ---------------------------------------------------------------------------
// Kernel 1: dequantize packed 4-bit weights into B^T bf16 layout (N x K)
//   W[k][n] = ((qw[k>>3][n] >> (4*(k&7))) & 0xF) * scales[n][k>>7] - zeros[n][k>>7]
// One block per n; each thread handles 2 qweight rows (kk), writes 16B chunks
// of the K-contiguous output row -> fully coalesced stores.
// ---------------------------------------------------------------------------
__global__ __launch_bounds__(256) void dequant_kernel(
        const uint32_t* __restrict__ qw,
        const float* __restrict__ scales,
        const float* __restrict__ zeros,
        __bf16* __restrict__ Wt) {
    const int n = blockIdx.x;
    const int tid = threadIdx.x;
#pragma unroll
    for (int it = 0; it < 2; ++it) {
        const int kk = tid + it * 256;             // 0..511
        const uint32_t q = qw[(size_t)kk * N_DIM + n];
        const int g = kk >> 4;                     // group = (kk*8)/128
        const float s = scales[(size_t)n * GROUPS + g];
        const float z = zeros[(size_t)n * GROUPS + g];
        bf16x8 w;
#pragma unroll
        for (int j = 0; j < 8; ++j) {
            float v = (float)((q >> (4 * j)) & 0xF) * s - z;
            w[j] = (__bf16)v;
        }
        *(bf16x8*)(Wt + (size_t)n * K_DIM + (size_t)kk * 8) = w;
    }
}

// ---------------------------------------------------------------------------
// Kernel 2: x fp32 -> bf16 (RNE), 8 elements per thread
// ---------------------------------------------------------------------------
__global__ __launch_bounds__(256) void xconv_kernel(
        const float* __restrict__ x, __bf16* __restrict__ xb) {
    const size_t i = ((size_t)blockIdx.x * 256 + threadIdx.x) * 8;
    const float4* p = (const float4*)(x + i);
    float4 a = p[0];
    float4 b = p[1];
    bf16x8 o;
    o[0] = (__bf16)a.x; o[1] = (__bf16)a.y; o[2] = (__bf16)a.z; o[3] = (__bf16)a.w;
    o[4] = (__bf16)b.x; o[5] = (__bf16)b.y; o[6] = (__bf16)b.z; o[7] = (__bf16)b.w;
    *(bf16x8*)(xb + i) = o;
}

// ---------------------------------------------------------------------------
// Kernel 3: bf16 GEMM, C = A(M x K) * Bt(N x K)^T + bias, fp32 out.
// 128x128 tile, BK=32, 256 threads = 4 waves in 2x2, each wave 64x64
// (4x4 MFMA 16x16x32 bf16). global_load_lds width-16 staging.
// ---------------------------------------------------------------------------
__global__ __launch_bounds__(256, 2) void gemm_kernel(
        const __bf16* __restrict__ A,    // M x K row-major
        const __bf16* __restrict__ Bt,   // N x K row-major
        const float* __restrict__ bias,  // N
        float* __restrict__ C) {         // M x N row-major
    __shared__ __align__(16) __bf16 As[128 * 32];   // [m][k], row stride 32
    __shared__ __align__(16) __bf16 Bs[128 * 32];   // [n][k], row stride 32

    const int tid  = threadIdx.x;
    const int wave = tid >> 6;
    const int lane = tid & 63;
    const int wm   = wave >> 1;      // 0..1
    const int wn   = wave & 1;       // 0..1
    const int quad = lane >> 4;      // 0..3
    const int l16  = lane & 15;

    const int m0 = blockIdx.y * 128;
    const int n0 = blockIdx.x * 128;

    f32x4 acc[4][4] = {};

    // --- staging chunk assignment -------------------------------------------
    // 512 chunks of 16B per tile; instr (wave,i) covers chunks (wave*2+i)*64 + lane.
    // chunk c -> row r = c>>2, k-offset (c&3)*8 elements.
    const int c0 = wave * 128 + lane;        // instr 0 chunk
    const int c1 = c0 + 64;                  // instr 1 chunk
    const __bf16* gA0 = A  + (size_t)(m0 + (c0 >> 2)) * K_DIM + (c0 & 3) * 8;
    const __bf16* gA1 = A  + (size_t)(m0 + (c1 >> 2)) * K_DIM + (c1 & 3) * 8;
    const __bf16* gB0 = Bt + (size_t)(n0 + (c0 >> 2)) * K_DIM + (c0 & 3) * 8;
    const __bf16* gB1 = Bt + (size_t)(n0 + (c1 >> 2)) * K_DIM + (c1 & 3) * 8;
    // wave-uniform LDS bases (HW adds lane*16)
    char* ldsA0 = (char*)As + (wave * 2 + 0) * 1024;
    char* ldsA1 = (char*)As + (wave * 2 + 1) * 1024;
    char* ldsB0 = (char*)Bs + (wave * 2 + 0) * 1024;
    char* ldsB1 = (char*)Bs + (wave * 2 + 1) * 1024;

    // fragment read base pointers (each frag: 8 consecutive-k bf16 = 16B)
    const __bf16* la = As + ((size_t)(wm * 64 + l16)) * 32 + quad * 8;
    const __bf16* lb = Bs + ((size_t)(wn * 64 + l16)) * 32 + quad * 8;

    for (int kt = 0; kt < K_DIM / 32; ++kt) {
        async16(gA0, ldsA0);
        async16(gA1, ldsA1);
        async16(gB0, ldsB0);
        async16(gB1, ldsB1);
        gA0 += 32; gA1 += 32; gB0 += 32; gB1 += 32;
        __syncthreads();                 // drain vmcnt, loads visible

        bf16x8 af[4], bf[4];
#pragma unroll
        for (int i = 0; i < 4; ++i) af[i] = *(const bf16x8*)(la + i * 16 * 32);
#pragma unroll
        for (int i = 0; i < 4; ++i) bf[i] = *(const bf16x8*)(lb + i * 16 * 32);

#pragma unroll
        for (int i = 0; i < 4; ++i)
#pragma unroll
            for (int j = 0; j < 4; ++j)
                acc[i][j] = __builtin_amdgcn_mfma_f32_16x16x32_bf16(
                    af[i], bf[j], acc[i][j], 0, 0, 0);

        __syncthreads();                 // LDS reads done before next overwrite
    }

    // --- epilogue: C[m][n] = acc + bias[n] ----------------------------------
    // C/D layout: col = lane&15, row = quad*4 + reg
#pragma unroll
    for (int j = 0; j < 4; ++j) {
        const int n = n0 + wn * 64 + j * 16 + l16;
        const float bv = bias[n];
#pragma unroll
        for (int i = 0; i < 4; ++i) {
            const int mb = m0 + wm * 64 + i * 16 + quad * 4;
#pragma unroll
            for (int r = 0; r < 4; ++r) {
                C[(size_t)(mb + r) * N_DIM + n] = acc[i][j][r] + bv;
            }
        }
    }
}

// ---------------------------------------------------------------------------
extern "C" void kernel_launch(void* const* d_in, const int* in_sizes, int n_in,
                              void* d_out, int out_size, void* d_ws, size_t ws_size,
                              hipStream_t stream) {
    const float*    x      = (const float*)d_in[0];
    const uint32_t* qw     = (const uint32_t*)d_in[1];
    const float*    scales = (const float*)d_in[2];
    const float*    zeros  = (const float*)d_in[3];
    const float*    bias   = (const float*)d_in[4];
    float*          out    = (float*)d_out;

    // workspace layout: Wt (N*K bf16 = 90,177,536 B) | xb (M*K bf16 = 33,554,432 B)
    __bf16* Wt = (__bf16*)d_ws;
    __bf16* xb = (__bf16*)((char*)d_ws + (size_t)N_DIM * K_DIM * sizeof(__bf16));

    dequant_kernel<<<N_DIM, 256, 0, stream>>>(qw, scales, zeros, Wt);
    xconv_kernel<<<(M_DIM * K_DIM) / (256 * 8), 256, 0, stream>>>(x, xb);

    dim3 grid(N_DIM / 128, M_DIM / 128);   // 86 x 32
    gemm_kernel<<<grid, 256, 0, stream>>>(xb, Wt, bias, out);
}

// Round 2
// 706.341 us; speedup vs baseline: 1.3002x; 1.3002x over previous
//
#include <hip/hip_runtime.h>
#include <hip/hip_bf16.h>
#include <cstdint>
#include <cstddef>

// Problem constants
#define K_DIM   4096          // INF
#define N_DIM   11008         // OUTF
#define M_DIM   4096          // 2*2048
#define GROUPS  32
#define QROWS   512           // INF*4/32

typedef __bf16 bf16x8 __attribute__((ext_vector_type(8)));
typedef float  f32x4  __attribute__((ext_vector_type(4)));

// ---------------------------------------------------------------------------
// async 16B global -> LDS (wave-uniform LDS base + lane*16 semantics)
// ---------------------------------------------------------------------------
__device__ __forceinline__ void async16(const void* g, void* lds) {
    __builtin_amdgcn_global_load_lds(
        (const __attribute__((address_space(1))) uint32_t*)g,
        (__attribute__((address_space(3))) uint32_t*)lds,
        16, 0, 0);
}

// ---------------------------------------------------------------------------
// Kernel 1: dequantize packed 4-bit weights into B^T bf16 layout (N x K).
// Tile: 64 n  x  32 qword-rows (=256 k). Reads coalesced along n, transposes
// through padded LDS, writes coalesced along k.
//   W[k][n] = ((qw[k>>3][n] >> (4*(k&7))) & 0xF) * scales[n][k>>7] - zeros[n][k>>7]
// ---------------------------------------------------------------------------
#define DQ_NN   64
#define DQ_KK   32
#define DQ_ROW  264   // 256 k-elements + 8 pad (16B) -> 528B row stride
__global__ __launch_bounds__(256) void dequant_kernel(
        const uint32_t* __restrict__ qw,
        const float* __restrict__ scales,
        const float* __restrict__ zeros,
        __bf16* __restrict__ Wt) {
    __shared__ __align__(16) __bf16 T[DQ_NN * DQ_ROW];   // 33,792 B

    const int n0  = blockIdx.x * DQ_NN;
    const int kk0 = blockIdx.y * DQ_KK;
    const int tid = threadIdx.x;

    // Phase 1: 64x32 = 2048 qwords, 8 per thread. Lanes consecutive in n.
#pragma unroll
    for (int it = 0; it < 8; ++it) {
        const int flat = it * 256 + tid;
        const int kk_l = flat >> 6;          // 0..31
        const int n_l  = flat & 63;          // 0..63
        const int kk   = kk0 + kk_l;
        const int n    = n0 + n_l;
        const uint32_t q = qw[(size_t)kk * N_DIM + n];
        const int g = kk >> 4;               // k-group = (kk*8)/128
        const float s = scales[(size_t)n * GROUPS + g];
        const float z = zeros[(size_t)n * GROUPS + g];
        bf16x8 w;
#pragma unroll
        for (int j = 0; j < 8; ++j) {
            float v = (float)((q >> (4 * j)) & 0xF) * s - z;
            w[j] = (__bf16)v;
        }
        *(bf16x8*)(&T[n_l * DQ_ROW + kk_l * 8]) = w;
    }
    __syncthreads();

    // Phase 2: write out 64 rows x 256 k, 16B chunks, lanes consecutive in k.
#pragma unroll
    for (int it = 0; it < 8; ++it) {
        const int flat = it * 256 + tid;
        const int n_l    = flat >> 5;        // 0..63
        const int kchunk = flat & 31;        // 0..31 (8 elems each)
        bf16x8 v = *(const bf16x8*)(&T[n_l * DQ_ROW + kchunk * 8]);
        *(bf16x8*)(Wt + (size_t)(n0 + n_l) * K_DIM + (size_t)kk0 * 8 + kchunk * 8) = v;
    }
}

// ---------------------------------------------------------------------------
// Kernel 2: x fp32 -> bf16 (RNE), 8 elements per thread
// ---------------------------------------------------------------------------
__global__ __launch_bounds__(256) void xconv_kernel(
        const float* __restrict__ x, __bf16* __restrict__ xb) {
    const size_t i = ((size_t)blockIdx.x * 256 + threadIdx.x) * 8;
    const float4* p = (const float4*)(x + i);
    float4 a = p[0];
    float4 b = p[1];
    bf16x8 o;
    o[0] = (__bf16)a.x; o[1] = (__bf16)a.y; o[2] = (__bf16)a.z; o[3] = (__bf16)a.w;
    o[4] = (__bf16)b.x; o[5] = (__bf16)b.y; o[6] = (__bf16)b.z; o[7] = (__bf16)b.w;
    *(bf16x8*)(xb + i) = o;
}

// ---------------------------------------------------------------------------
// Kernel 3: bf16 GEMM, C = A(M x K) * Bt(N x K)^T + bias, fp32 out.
// 128x128 tile, BK=32, 256 threads = 4 waves in 2x2, each wave 64x64
// (4x4 MFMA 16x16x32 bf16). global_load_lds width-16 staging.
// 1-D grid with 16N x 32M supertile swizzle for L2 locality.
// ---------------------------------------------------------------------------
#define GN 86   // N_DIM/128
#define GM 32   // M_DIM/128
#define SN 16   // N-tiles per supertile column group
__global__ __launch_bounds__(256, 4) void gemm_kernel(
        const __bf16* __restrict__ A,    // M x K row-major
        const __bf16* __restrict__ Bt,   // N x K row-major
        const float* __restrict__ bias,  // N
        float* __restrict__ C) {         // M x N row-major
    __shared__ __align__(16) __bf16 As[128 * 32];   // [m][k], row stride 32
    __shared__ __align__(16) __bf16 Bs[128 * 32];   // [n][k], row stride 32

    const int tid  = threadIdx.x;
    const int wave = tid >> 6;
    const int lane = tid & 63;
    const int wm   = wave >> 1;      // 0..1
    const int wn   = wave & 1;       // 0..1
    const int quad = lane >> 4;      // 0..3
    const int l16  = lane & 15;

    // --- supertile swizzle: consecutive blocks form a 16N x 32M rectangle ---
    const int bid = blockIdx.x;
    const int g   = bid >> 9;                 // / (GM*SN) = /512
    const int rem = bid & 511;
    int n_t, m_t;
    const int snw = (GN - g * SN) < SN ? (GN - g * SN) : SN;
    if (snw == SN) { n_t = g * SN + (rem & (SN - 1)); m_t = rem >> 4; }
    else           { n_t = g * SN + rem % snw;        m_t = rem / snw; }

    const int m0 = m_t * 128;
    const int n0 = n_t * 128;

    f32x4 acc[4][4] = {};

    // --- staging chunk assignment -------------------------------------------
    // 512 chunks of 16B per tile; instr (wave,i) covers chunks (wave*2+i)*64 + lane.
    // chunk c -> row r = c>>2, k-offset (c&3)*8 elements.
    const int c0 = wave * 128 + lane;        // instr 0 chunk
    const int c1 = c0 + 64;                  // instr 1 chunk
    const __bf16* gA0 = A  + (size_t)(m0 + (c0 >> 2)) * K_DIM + (c0 & 3) * 8;
    const __bf16* gA1 = A  + (size_t)(m0 + (c1 >> 2)) * K_DIM + (c1 & 3) * 8;
    const __bf16* gB0 = Bt + (size_t)(n0 + (c0 >> 2)) * K_DIM + (c0 & 3) * 8;
    const __bf16* gB1 = Bt + (size_t)(n0 + (c1 >> 2)) * K_DIM + (c1 & 3) * 8;
    // wave-uniform LDS bases (HW adds lane*16)
    char* ldsA0 = (char*)As + (wave * 2 + 0) * 1024;
    char* ldsA1 = (char*)As + (wave * 2 + 1) * 1024;
    char* ldsB0 = (char*)Bs + (wave * 2 + 0) * 1024;
    char* ldsB1 = (char*)Bs + (wave * 2 + 1) * 1024;

    // fragment read base pointers (each frag: 8 consecutive-k bf16 = 16B)
    const __bf16* la = As + ((size_t)(wm * 64 + l16)) * 32 + quad * 8;
    const __bf16* lb = Bs + ((size_t)(wn * 64 + l16)) * 32 + quad * 8;

    for (int kt = 0; kt < K_DIM / 32; ++kt) {
        async16(gA0, ldsA0);
        async16(gA1, ldsA1);
        async16(gB0, ldsB0);
        async16(gB1, ldsB1);
        gA0 += 32; gA1 += 32; gB0 += 32; gB1 += 32;
        __syncthreads();                 // drain vmcnt, loads visible

        bf16x8 af[4], bf[4];
#pragma unroll
        for (int i = 0; i < 4; ++i) af[i] = *(const bf16x8*)(la + i * 16 * 32);
#pragma unroll
        for (int i = 0; i < 4; ++i) bf[i] = *(const bf16x8*)(lb + i * 16 * 32);

#pragma unroll
        for (int i = 0; i < 4; ++i)
#pragma unroll
            for (int j = 0; j < 4; ++j)
                acc[i][j] = __builtin_amdgcn_mfma_f32_16x16x32_bf16(
                    af[i], bf[j], acc[i][j], 0, 0, 0);

        __syncthreads();                 // LDS reads done before next overwrite
    }

    // --- epilogue: C[m][n] = acc + bias[n] ----------------------------------
    // C/D layout: col = lane&15, row = quad*4 + reg
#pragma unroll
    for (int j = 0; j < 4; ++j) {
        const int n = n0 + wn * 64 + j * 16 + l16;
        const float bv = bias[n];
#pragma unroll
        for (int i = 0; i < 4; ++i) {
            const int mb = m0 + wm * 64 + i * 16 + quad * 4;
#pragma unroll
            for (int r = 0; r < 4; ++r) {
                C[(size_t)(mb + r) * N_DIM + n] = acc[i][j][r] + bv;
            }
        }
    }
}

// ---------------------------------------------------------------------------
extern "C" void kernel_launch(void* const* d_in, const int* in_sizes, int n_in,
                              void* d_out, int out_size, void* d_ws, size_t ws_size,
                              hipStream_t stream) {
    const float*    x      = (const float*)d_in[0];
    const uint32_t* qw     = (const uint32_t*)d_in[1];
    const float*    scales = (const float*)d_in[2];
    const float*    zeros  = (const float*)d_in[3];
    const float*    bias   = (const float*)d_in[4];
    float*          out    = (float*)d_out;

    // workspace layout: Wt (N*K bf16 = 90,177,536 B) | xb (M*K bf16 = 33,554,432 B)
    __bf16* Wt = (__bf16*)d_ws;
    __bf16* xb = (__bf16*)((char*)d_ws + (size_t)N_DIM * K_DIM * sizeof(__bf16));

    dim3 dq_grid(N_DIM / DQ_NN, QROWS / DQ_KK);   // 172 x 16
    dequant_kernel<<<dq_grid, 256, 0, stream>>>(qw, scales, zeros, Wt);
    xconv_kernel<<<(M_DIM * K_DIM) / (256 * 8), 256, 0, stream>>>(x, xb);

    gemm_kernel<<<GN * GM, 256, 0, stream>>>(xb, Wt, bias, out);
}